// Round 2
// baseline (862.126 us; speedup 1.0000x reference)
//
#include <hip/hip_runtime.h>
#include <hip/hip_bf16.h>

// Problem constants (from reference)
#define S 2048
#define W 96
#define E 100
#define H 100
#define PD 50

__device__ __forceinline__ float fast_rcp(float x) { return __builtin_amdgcn_rcpf(x); }

// Overflow-safe fast tanh: e = exp(-2|x|) in (0,1], never overflows.
__device__ __forceinline__ float fast_tanh(float x) {
    float ax = fabsf(x);
    float e  = __expf(-2.0f * ax);
    float r  = (1.0f - e) * fast_rcp(1.0f + e);
    return copysignf(r, x);
}

__device__ __forceinline__ float fast_sigmoid(float x) {
    return fast_rcp(1.0f + __expf(-x));
}

// K1: ragged-prefix mean pool over word embeddings + doc_feat accumulation
__global__ __launch_bounds__(128) void k_sent(const int* __restrict__ x,
                                              const float* __restrict__ word_emb,
                                              float* __restrict__ sent,
                                              float* __restrict__ doc_sum) {
    __shared__ int toks[W];
    __shared__ int s_len;
    const int i = blockIdx.x, t = threadIdx.x;
    if (t == 0) s_len = 0;
    __syncthreads();
    if (t < W) {
        int tok = x[i * W + t];
        toks[t] = tok;
        if (tok > 0) atomicAdd(&s_len, 1);
    }
    __syncthreads();
    const int len = s_len;
    if (t < E) {
        float acc = 0.0f;
        for (int j = 0; j < len; ++j)
            acc += word_emb[toks[j] * E + t];   // coalesced across t
        float val = acc / (float)max(len, 1);
        sent[i * E + t] = val;
        atomicAdd(&doc_sum[t], val * (1.0f / (float)S));
    }
}

// K2: doc = tanh(doc_feat @ fc1_w.T + fc1_b); cvec = Wc + Ws @ doc
__global__ __launch_bounds__(128) void k_doc(const float* __restrict__ doc_sum,
                                             const float* __restrict__ fc1_w,
                                             const float* __restrict__ fc1_b,
                                             const float* __restrict__ Wc,
                                             const float* __restrict__ Ws,
                                             float* __restrict__ cvec) {
    __shared__ float s_df[E];
    __shared__ float s_doc[H];
    const int t = threadIdx.x;
    if (t < E) s_df[t] = doc_sum[t];
    __syncthreads();
    if (t < H) {
        float acc = fc1_b[t];
        for (int k = 0; k < E; ++k) acc += s_df[k] * fc1_w[t * E + k];
        s_doc[t] = tanhf(acc);
    }
    __syncthreads();
    if (t < H) {
        float c = Wc[t];
        for (int j = 0; j < H; ++j) c += Ws[t * H + j] * s_doc[j];
        cvec[t] = c;
    }
}

// K3: per-row h = tanh(sent@fc2_w.T + b), comb[i][k] = (hWr[i][k], h[i][k]) interleaved,
//     pre[i] = h . cvec + pos . Wp + b
__global__ __launch_bounds__(128) void k_row(const float* __restrict__ sent,
                                             const float* __restrict__ fc2_w,
                                             const float* __restrict__ fc2_b,
                                             const float* __restrict__ Wr,
                                             const float* __restrict__ cvec,
                                             const float* __restrict__ pos_emb,
                                             const float* __restrict__ Wp,
                                             const float* __restrict__ bptr,
                                             float* __restrict__ comb,   // [S][2*H] interleaved
                                             float* __restrict__ pre) {
    __shared__ float s_sent[E];
    __shared__ float s_h[H];
    __shared__ float red[128];
    const int i = blockIdx.x, t = threadIdx.x;
    if (t < E) s_sent[t] = sent[i * E + t];
    __syncthreads();
    float hv = 0.0f;
    if (t < H) {
        float acc = fc2_b[t];
        for (int k = 0; k < E; ++k) acc += s_sent[k] * fc2_w[t * E + k];
        hv = tanhf(acc);
        s_h[t] = hv;
    }
    __syncthreads();
    if (t < H) {
        float acc = 0.0f;
        for (int k = 0; k < H; ++k) acc += s_h[k] * Wr[k * H + t];   // coalesced across t
        comb[i * (2 * H) + 2 * t]     = acc;  // hWr
        comb[i * (2 * H) + 2 * t + 1] = hv;   // h
    }
    float p = 0.0f;
    if (t < H) p = hv * cvec[t];
    if (t < PD) p += pos_emb[i * PD + t] * Wp[t];
    red[t] = p;
    __syncthreads();
    for (int m = 64; m > 0; m >>= 1) {
        if (t < m) red[t] += red[t + m];
        __syncthreads();
    }
    if (t == 0) pre[i] = red[0] + bptr[0];
}

// K4: the sequential scan. One wave; lane l owns s[l] and s[l+64] (l<36).
__global__ __launch_bounds__(64) void k_scan(const float* __restrict__ comb,
                                             const float* __restrict__ pre,
                                             float* __restrict__ out) {
    const int l = threadIdx.x;
    const bool hi = l < (H - 64);   // 36 lanes carry a second element
    const float2* __restrict__ c2 = (const float2*)comb;  // [S][H] of (hWr, h)

    float s0 = 0.0f, s1 = 0.0f;

    // 2-deep software pipeline of the per-step loads
    float2 a0_0 = c2[l];
    float2 a1_0 = hi ? c2[64 + l] : make_float2(0.f, 0.f);
    float  pr_0 = pre[0];
    float2 a0_1 = c2[H + l];
    float2 a1_1 = hi ? c2[H + 64 + l] : make_float2(0.f, 0.f);
    float  pr_1 = pre[1];

    for (int i = 0; i < S; ++i) {
        const float2 ca0 = a0_0;
        const float2 ca1 = a1_0;
        const float  cpr = pr_0;
        a0_0 = a0_1; a1_0 = a1_1; pr_0 = pr_1;
        if (i + 2 < S) {
            const float2* p = c2 + (size_t)(i + 2) * H;
            a0_1 = p[l];
            a1_1 = hi ? p[64 + l] : make_float2(0.f, 0.f);
            pr_1 = pre[i + 2];
        }

        float t0 = fast_tanh(s0);
        float t1 = fast_tanh(s1);
        float part = ca0.x * t0 + ca1.x * t1;
        #pragma unroll
        for (int m = 32; m > 0; m >>= 1)
            part += __shfl_xor(part, m, 64);
        float logit = cpr - part;
        float p = fast_sigmoid(logit);
        s0 = fmaf(ca0.y, p, s0);
        s1 = fmaf(ca1.y, p, s1);
        if (l == 0) out[i] = p;
    }
}

extern "C" void kernel_launch(void* const* d_in, const int* in_sizes, int n_in,
                              void* d_out, int out_size, void* d_ws, size_t ws_size,
                              hipStream_t stream) {
    const int*   x        = (const int*)  d_in[0];
    const float* word_emb = (const float*)d_in[1];
    const float* pos_emb  = (const float*)d_in[2];
    const float* fc1_w    = (const float*)d_in[3];
    const float* fc1_b    = (const float*)d_in[4];
    const float* fc2_w    = (const float*)d_in[5];
    const float* fc2_b    = (const float*)d_in[6];
    const float* Wc       = (const float*)d_in[7];
    const float* Ws       = (const float*)d_in[8];
    const float* Wr       = (const float*)d_in[9];
    const float* Wp       = (const float*)d_in[10];
    const float* bptr     = (const float*)d_in[11];
    float* out = (float*)d_out;

    float* wsf      = (float*)d_ws;
    float* doc_sum  = wsf;                 // 100 (zeroed each call)
    float* cvec     = wsf + 128;           // 100
    float* sent     = wsf + 256;           // S*E = 204800
    float* comb     = sent + S * E;        // S*2H = 409600
    float* pre      = comb + S * 2 * H;    // S = 2048

    hipMemsetAsync(doc_sum, 0, E * sizeof(float), stream);
    k_sent<<<S, 128, 0, stream>>>(x, word_emb, sent, doc_sum);
    k_doc<<<1, 128, 0, stream>>>(doc_sum, fc1_w, fc1_b, Wc, Ws, cvec);
    k_row<<<S, 128, 0, stream>>>(sent, fc2_w, fc2_b, Wr, cvec, pos_emb, Wp, bptr, comb, pre);
    k_scan<<<1, 64, 0, stream>>>(comb, pre, out);
}

// Round 3
// 675.171 us; speedup vs baseline: 1.2769x; 1.2769x over previous
//
#include <hip/hip_runtime.h>
#include <hip/hip_bf16.h>

// Problem constants (from reference)
#define S 2048
#define W 96
#define E 100
#define H 100
#define PD 50

__device__ __forceinline__ float fast_rcp(float x) { return __builtin_amdgcn_rcpf(x); }

// Overflow-safe fast tanh: e = exp(-2|x|) in (0,1], never overflows.
__device__ __forceinline__ float fast_tanh(float x) {
    float ax = fabsf(x);
    float e  = __expf(-2.0f * ax);
    float r  = (1.0f - e) * fast_rcp(1.0f + e);
    return copysignf(r, x);
}

// One DPP reduction stage: x += dpp_move(x). VALU latency, no LDS.
template<int CTRL, int RM, bool BND>
__device__ __forceinline__ float dpp_add(float x) {
    int t = __builtin_amdgcn_update_dpp(0, __float_as_int(x), CTRL, RM, 0xf, BND);
    return x + __int_as_float(t);
}

// Full-wave (64-lane) sum; returns the total as a wave-uniform value.
// row_shr:1/2/4/8 within each row of 16, then row_bcast:15 (rows 1,3),
// row_bcast:31 (rows 2,3); lane 63 holds the total; readlane broadcasts.
__device__ __forceinline__ float wave_sum_bcast(float x) {
    x = dpp_add<0x111, 0xf, true >(x);  // row_shr:1
    x = dpp_add<0x112, 0xf, true >(x);  // row_shr:2
    x = dpp_add<0x114, 0xf, true >(x);  // row_shr:4
    x = dpp_add<0x118, 0xf, true >(x);  // row_shr:8
    x = dpp_add<0x142, 0xa, false>(x);  // row_bcast:15 -> rows 1,3
    x = dpp_add<0x143, 0xc, false>(x);  // row_bcast:31 -> rows 2,3
    return __int_as_float(__builtin_amdgcn_readlane(__float_as_int(x), 63));
}

// K1: ragged-prefix mean pool over word embeddings + doc_feat accumulation
__global__ __launch_bounds__(128) void k_sent(const int* __restrict__ x,
                                              const float* __restrict__ word_emb,
                                              float* __restrict__ sent,
                                              float* __restrict__ doc_sum) {
    __shared__ int toks[W];
    __shared__ int s_len;
    const int i = blockIdx.x, t = threadIdx.x;
    if (t == 0) s_len = 0;
    __syncthreads();
    if (t < W) {
        int tok = x[i * W + t];
        toks[t] = tok;
        if (tok > 0) atomicAdd(&s_len, 1);
    }
    __syncthreads();
    const int len = s_len;
    if (t < E) {
        float acc = 0.0f;
        for (int j = 0; j < len; ++j)
            acc += word_emb[toks[j] * E + t];   // coalesced across t
        float val = acc / (float)max(len, 1);
        sent[i * E + t] = val;
        atomicAdd(&doc_sum[t], val * (1.0f / (float)S));
    }
}

// K2: doc = tanh(doc_feat @ fc1_w.T + fc1_b); cvec = Wc + Ws @ doc
__global__ __launch_bounds__(128) void k_doc(const float* __restrict__ doc_sum,
                                             const float* __restrict__ fc1_w,
                                             const float* __restrict__ fc1_b,
                                             const float* __restrict__ Wc,
                                             const float* __restrict__ Ws,
                                             float* __restrict__ cvec) {
    __shared__ float s_df[E];
    __shared__ float s_doc[H];
    const int t = threadIdx.x;
    if (t < E) s_df[t] = doc_sum[t];
    __syncthreads();
    if (t < H) {
        float acc = fc1_b[t];
        for (int k = 0; k < E; ++k) acc += s_df[k] * fc1_w[t * E + k];
        s_doc[t] = tanhf(acc);
    }
    __syncthreads();
    if (t < H) {
        float c = Wc[t];
        for (int j = 0; j < H; ++j) c += Ws[t * H + j] * s_doc[j];
        cvec[t] = c;
    }
}

// K3: per-row h = tanh(sent@fc2_w.T + b), comb[i][k] = (hWr[i][k], h[i][k]) interleaved,
//     pre[i] = h . cvec + pos . Wp + b
__global__ __launch_bounds__(128) void k_row(const float* __restrict__ sent,
                                             const float* __restrict__ fc2_w,
                                             const float* __restrict__ fc2_b,
                                             const float* __restrict__ Wr,
                                             const float* __restrict__ cvec,
                                             const float* __restrict__ pos_emb,
                                             const float* __restrict__ Wp,
                                             const float* __restrict__ bptr,
                                             float* __restrict__ comb,   // [S][2*H] interleaved
                                             float* __restrict__ pre) {
    __shared__ float s_sent[E];
    __shared__ float s_h[H];
    __shared__ float red[128];
    const int i = blockIdx.x, t = threadIdx.x;
    if (t < E) s_sent[t] = sent[i * E + t];
    __syncthreads();
    float hv = 0.0f;
    if (t < H) {
        float acc = fc2_b[t];
        for (int k = 0; k < E; ++k) acc += s_sent[k] * fc2_w[t * E + k];
        hv = tanhf(acc);
        s_h[t] = hv;
    }
    __syncthreads();
    if (t < H) {
        float acc = 0.0f;
        for (int k = 0; k < H; ++k) acc += s_h[k] * Wr[k * H + t];   // coalesced across t
        comb[i * (2 * H) + 2 * t]     = acc;  // hWr
        comb[i * (2 * H) + 2 * t + 1] = hv;   // h
    }
    float p = 0.0f;
    if (t < H) p = hv * cvec[t];
    if (t < PD) p += pos_emb[i * PD + t] * Wp[t];
    red[t] = p;
    __syncthreads();
    for (int m = 64; m > 0; m >>= 1) {
        if (t < m) red[t] += red[t + m];
        __syncthreads();
    }
    if (t == 0) pre[i] = red[0] + bptr[0];
}

// K4: the sequential scan. One wave; lane l owns s[l] and s[l+64] (l<36).
// 4-deep software pipeline; DPP-based wave reduction on the critical path.
__global__ __launch_bounds__(64) void k_scan(const float* __restrict__ comb,
                                             const float* __restrict__ pre,
                                             float* __restrict__ out) {
    const int l = threadIdx.x;
    const bool hi = l < (H - 64);   // 36 lanes carry a second element
    const float2* __restrict__ c2 = (const float2*)comb;  // [S][H] of (hWr, h)

    float s0 = 0.0f, s1 = 0.0f;

    // 4-deep prefetch pipeline (statically indexed via full unroll)
    float2 A[4], B[4];
    float  CQ[4];   // -log2e * pre[i], folded off the critical path
    #pragma unroll
    for (int u = 0; u < 4; ++u) {
        const float2* p = c2 + (size_t)u * H;
        A[u] = p[l];
        B[u] = hi ? p[64 + l] : make_float2(0.f, 0.f);
        CQ[u] = -1.44269504f * pre[u];
    }

    for (int base = 0; base < S; base += 4) {
        #pragma unroll
        for (int u = 0; u < 4; ++u) {
            const int i = base + u;
            const float2 ca = A[u];
            const float2 cb = B[u];
            const float  cq = CQ[u];
            if (i + 4 < S) {   // prefetch i+4 into slot u (off critical path)
                const float2* p = c2 + (size_t)(i + 4) * H;
                A[u] = p[l];
                B[u] = hi ? p[64 + l] : make_float2(0.f, 0.f);
                CQ[u] = -1.44269504f * pre[i + 4];
            }
            float t0 = fast_tanh(s0);
            float t1 = fast_tanh(s1);
            float part = fmaf(ca.x, t0, cb.x * t1);
            float total = wave_sum_bcast(part);
            // prob = sigmoid(pre - total) = 1 / (1 + exp2(log2e*total - log2e*pre))
            float e = exp2f(fmaf(1.44269504f, total, cq));
            float prob = fast_rcp(1.0f + e);
            s0 = fmaf(ca.y, prob, s0);
            s1 = fmaf(cb.y, prob, s1);
            if (l == 0) out[i] = prob;
        }
    }
}

extern "C" void kernel_launch(void* const* d_in, const int* in_sizes, int n_in,
                              void* d_out, int out_size, void* d_ws, size_t ws_size,
                              hipStream_t stream) {
    const int*   x        = (const int*)  d_in[0];
    const float* word_emb = (const float*)d_in[1];
    const float* pos_emb  = (const float*)d_in[2];
    const float* fc1_w    = (const float*)d_in[3];
    const float* fc1_b    = (const float*)d_in[4];
    const float* fc2_w    = (const float*)d_in[5];
    const float* fc2_b    = (const float*)d_in[6];
    const float* Wc       = (const float*)d_in[7];
    const float* Ws       = (const float*)d_in[8];
    const float* Wr       = (const float*)d_in[9];
    const float* Wp       = (const float*)d_in[10];
    const float* bptr     = (const float*)d_in[11];
    float* out = (float*)d_out;

    float* wsf      = (float*)d_ws;
    float* doc_sum  = wsf;                 // 100 (zeroed each call)
    float* cvec     = wsf + 128;           // 100
    float* sent     = wsf + 256;           // S*E = 204800
    float* comb     = sent + S * E;        // S*2H = 409600
    float* pre      = comb + S * 2 * H;    // S = 2048

    hipMemsetAsync(doc_sum, 0, E * sizeof(float), stream);
    k_sent<<<S, 128, 0, stream>>>(x, word_emb, sent, doc_sum);
    k_doc<<<1, 128, 0, stream>>>(doc_sum, fc1_w, fc1_b, Wc, Ws, cvec);
    k_row<<<S, 128, 0, stream>>>(sent, fc2_w, fc2_b, Wr, cvec, pos_emb, Wp, bptr, comb, pre);
    k_scan<<<1, 64, 0, stream>>>(comb, pre, out);
}

// Round 4
// 442.308 us; speedup vs baseline: 1.9492x; 1.5265x over previous
//
#include <hip/hip_runtime.h>
#include <hip/hip_bf16.h>

// Problem constants (from reference)
#define S 2048
#define W 96
#define E 100
#define H 100
#define PD 50
#define DEPTH 8   // scan prefetch pipeline depth

__device__ __forceinline__ float fast_rcp(float x) { return __builtin_amdgcn_rcpf(x); }

// Overflow-safe fast tanh: e = exp(-2|x|) in (0,1], never overflows.
__device__ __forceinline__ float fast_tanh(float x) {
    float ax = fabsf(x);
    float e  = __expf(-2.0f * ax);
    float r  = (1.0f - e) * fast_rcp(1.0f + e);
    return copysignf(r, x);
}

// One DPP reduction stage: x += dpp_move(x). VALU latency, no LDS.
template<int CTRL, int RM, bool BND>
__device__ __forceinline__ float dpp_add(float x) {
    int t = __builtin_amdgcn_update_dpp(0, __float_as_int(x), CTRL, RM, 0xf, BND);
    return x + __int_as_float(t);
}

// Full-wave (64-lane) sum; returns total as a wave-uniform value.
__device__ __forceinline__ float wave_sum_bcast(float x) {
    x = dpp_add<0x111, 0xf, true >(x);  // row_shr:1
    x = dpp_add<0x112, 0xf, true >(x);  // row_shr:2
    x = dpp_add<0x114, 0xf, true >(x);  // row_shr:4
    x = dpp_add<0x118, 0xf, true >(x);  // row_shr:8
    x = dpp_add<0x142, 0xa, false>(x);  // row_bcast:15 -> rows 1,3
    x = dpp_add<0x143, 0xc, false>(x);  // row_bcast:31 -> rows 2,3
    return __int_as_float(__builtin_amdgcn_readlane(__float_as_int(x), 63));
}

// K1: ragged-prefix mean pool over word embeddings + doc_feat accumulation
__global__ __launch_bounds__(128) void k_sent(const int* __restrict__ x,
                                              const float* __restrict__ word_emb,
                                              float* __restrict__ sent,
                                              float* __restrict__ doc_sum) {
    __shared__ int toks[W];
    __shared__ int s_len;
    const int i = blockIdx.x, t = threadIdx.x;
    if (t == 0) s_len = 0;
    __syncthreads();
    if (t < W) {
        int tok = x[i * W + t];
        toks[t] = tok;
        if (tok > 0) atomicAdd(&s_len, 1);
    }
    __syncthreads();
    const int len = s_len;
    if (t < E) {
        float acc = 0.0f;
        for (int j = 0; j < len; ++j)
            acc += word_emb[toks[j] * E + t];   // coalesced across t
        float val = acc / (float)max(len, 1);
        sent[i * E + t] = val;
        atomicAdd(&doc_sum[t], val * (1.0f / (float)S));
    }
}

// K2: doc = tanh(doc_feat @ fc1_w.T + fc1_b); cvec = Wc + Ws @ doc
__global__ __launch_bounds__(128) void k_doc(const float* __restrict__ doc_sum,
                                             const float* __restrict__ fc1_w,
                                             const float* __restrict__ fc1_b,
                                             const float* __restrict__ Wc,
                                             const float* __restrict__ Ws,
                                             float* __restrict__ cvec) {
    __shared__ float s_df[E];
    __shared__ float s_doc[H];
    const int t = threadIdx.x;
    if (t < E) s_df[t] = doc_sum[t];
    __syncthreads();
    if (t < H) {
        float acc = fc1_b[t];
        for (int k = 0; k < E; ++k) acc += s_df[k] * fc1_w[t * E + k];
        s_doc[t] = tanhf(acc);
    }
    __syncthreads();
    if (t < H) {
        float c = Wc[t];
        for (int j = 0; j < H; ++j) c += Ws[t * H + j] * s_doc[j];
        cvec[t] = c;
    }
}

// K3: per-row h = tanh(sent@fc2_w.T + b), comb[i][k] = (hWr[i][k], h[i][k]) interleaved,
//     cq[i] = -log2e * (h.cvec + pos.Wp + b)   (pre-folded for the scan's sigmoid)
__global__ __launch_bounds__(128) void k_row(const float* __restrict__ sent,
                                             const float* __restrict__ fc2_w,
                                             const float* __restrict__ fc2_b,
                                             const float* __restrict__ Wr,
                                             const float* __restrict__ cvec,
                                             const float* __restrict__ pos_emb,
                                             const float* __restrict__ Wp,
                                             const float* __restrict__ bptr,
                                             float* __restrict__ comb,   // [S][2*H] interleaved
                                             float* __restrict__ cq) {
    __shared__ float s_sent[E];
    __shared__ float s_h[H];
    __shared__ float red[128];
    const int i = blockIdx.x, t = threadIdx.x;
    if (t < E) s_sent[t] = sent[i * E + t];
    __syncthreads();
    float hv = 0.0f;
    if (t < H) {
        float acc = fc2_b[t];
        for (int k = 0; k < E; ++k) acc += s_sent[k] * fc2_w[t * E + k];
        hv = tanhf(acc);
        s_h[t] = hv;
    }
    __syncthreads();
    if (t < H) {
        float acc = 0.0f;
        for (int k = 0; k < H; ++k) acc += s_h[k] * Wr[k * H + t];   // coalesced across t
        comb[i * (2 * H) + 2 * t]     = acc;  // hWr
        comb[i * (2 * H) + 2 * t + 1] = hv;   // h
    }
    float p = 0.0f;
    if (t < H) p = hv * cvec[t];
    if (t < PD) p += pos_emb[i * PD + t] * Wp[t];
    red[t] = p;
    __syncthreads();
    for (int m = 64; m > 0; m >>= 1) {
        if (t < m) red[t] += red[t + m];
        __syncthreads();
    }
    if (t == 0) cq[i] = -1.44269504f * (red[0] + bptr[0]);
}

// K4: the sequential scan. One wave; lane l owns s[l] and s[l+64] (l<36).
// 8-deep branch-free prefetch pipeline; loads are raw (no arithmetic on
// prefetched data -> no vmcnt(0) drain); DPP wave reduction on critical path.
__global__ __launch_bounds__(64) void k_scan(const float* __restrict__ comb,
                                             const float* __restrict__ cq,
                                             float* __restrict__ out) {
    const int l = threadIdx.x;
    const bool hi = l < (H - 64);   // 36 lanes carry a second element
    const float2* __restrict__ c2 = (const float2*)comb;  // [S][H] of (hWr, h)

    float s0 = 0.0f, s1 = 0.0f;

    float2 A[DEPTH], B[DEPTH];
    float  Q[DEPTH];
    #pragma unroll
    for (int u = 0; u < DEPTH; ++u) {
        const float2* p = c2 + (size_t)u * H;
        A[u] = p[l];
        B[u] = hi ? p[64 + l] : make_float2(0.f, 0.f);
        Q[u] = cq[u];
    }

    for (int base = 0; base < S; base += DEPTH) {
        #pragma unroll
        for (int u = 0; u < DEPTH; ++u) {
            const int i = base + u;
            const float2 ca = A[u];
            const float2 cb = B[u];
            const float  q  = Q[u];
            // branch-free prefetch, clamped index (always valid, always issued)
            const int j = (i + DEPTH < S) ? (i + DEPTH) : (S - 1);
            const float2* p = c2 + (size_t)j * H;
            A[u] = p[l];
            B[u] = hi ? p[64 + l] : make_float2(0.f, 0.f);
            Q[u] = cq[j];

            float t0 = fast_tanh(s0);
            float t1 = fast_tanh(s1);
            float part = fmaf(ca.x, t0, cb.x * t1);
            float total = wave_sum_bcast(part);
            // prob = sigmoid(pre - total) = 1/(1 + exp2(log2e*total + q))
            float e = exp2f(fmaf(1.44269504f, total, q));
            float prob = fast_rcp(1.0f + e);
            s0 = fmaf(ca.y, prob, s0);
            s1 = fmaf(cb.y, prob, s1);
            if (l == 0) out[i] = prob;
        }
    }
}

extern "C" void kernel_launch(void* const* d_in, const int* in_sizes, int n_in,
                              void* d_out, int out_size, void* d_ws, size_t ws_size,
                              hipStream_t stream) {
    const int*   x        = (const int*)  d_in[0];
    const float* word_emb = (const float*)d_in[1];
    const float* pos_emb  = (const float*)d_in[2];
    const float* fc1_w    = (const float*)d_in[3];
    const float* fc1_b    = (const float*)d_in[4];
    const float* fc2_w    = (const float*)d_in[5];
    const float* fc2_b    = (const float*)d_in[6];
    const float* Wc       = (const float*)d_in[7];
    const float* Ws       = (const float*)d_in[8];
    const float* Wr       = (const float*)d_in[9];
    const float* Wp       = (const float*)d_in[10];
    const float* bptr     = (const float*)d_in[11];
    float* out = (float*)d_out;

    float* wsf      = (float*)d_ws;
    float* doc_sum  = wsf;                 // 100 (zeroed each call)
    float* cvec     = wsf + 128;           // 100
    float* sent     = wsf + 256;           // S*E = 204800
    float* comb     = sent + S * E;        // S*2H = 409600
    float* cq       = comb + S * 2 * H;    // S = 2048

    hipMemsetAsync(doc_sum, 0, E * sizeof(float), stream);
    k_sent<<<S, 128, 0, stream>>>(x, word_emb, sent, doc_sum);
    k_doc<<<1, 128, 0, stream>>>(doc_sum, fc1_w, fc1_b, Wc, Ws, cvec);
    k_row<<<S, 128, 0, stream>>>(sent, fc2_w, fc2_b, Wr, cvec, pos_emb, Wp, bptr, comb, cq);
    k_scan<<<1, 64, 0, stream>>>(comb, cq, out);
}

// Round 5
// 425.227 us; speedup vs baseline: 2.0275x; 1.0402x over previous
//
#include <hip/hip_runtime.h>
#include <hip/hip_bf16.h>

// Problem constants (from reference)
#define S 2048
#define W 96
#define E 100
#define H 100
#define PD 50
#define DEPTH 8   // scan prefetch pipeline depth

__device__ __forceinline__ float fast_rcp(float x) { return __builtin_amdgcn_rcpf(x); }

// Overflow-safe fast tanh: e = exp(-2|x|) in (0,1], never overflows.
__device__ __forceinline__ float fast_tanh(float x) {
    float ax = fabsf(x);
    float e  = __expf(-2.0f * ax);
    float r  = (1.0f - e) * fast_rcp(1.0f + e);
    return copysignf(r, x);
}

// One DPP reduction stage: x += dpp_move(x). VALU latency, no LDS.
template<int CTRL, int RM, bool BND>
__device__ __forceinline__ float dpp_add(float x) {
    int t = __builtin_amdgcn_update_dpp(0, __float_as_int(x), CTRL, RM, 0xf, BND);
    return x + __int_as_float(t);
}

// Full-wave (64-lane) sum; returns total as a wave-uniform value.
__device__ __forceinline__ float wave_sum_bcast(float x) {
    x = dpp_add<0x111, 0xf, true >(x);  // row_shr:1
    x = dpp_add<0x112, 0xf, true >(x);  // row_shr:2
    x = dpp_add<0x114, 0xf, true >(x);  // row_shr:4
    x = dpp_add<0x118, 0xf, true >(x);  // row_shr:8
    x = dpp_add<0x142, 0xa, false>(x);  // row_bcast:15 -> rows 1,3
    x = dpp_add<0x143, 0xc, false>(x);  // row_bcast:31 -> rows 2,3
    return __int_as_float(__builtin_amdgcn_readlane(__float_as_int(x), 63));
}

// K1: ragged-prefix mean pool over word embeddings + doc_feat accumulation
__global__ __launch_bounds__(128) void k_sent(const int* __restrict__ x,
                                              const float* __restrict__ word_emb,
                                              float* __restrict__ sent,
                                              float* __restrict__ doc_sum) {
    __shared__ int toks[W];
    __shared__ int s_len;
    const int i = blockIdx.x, t = threadIdx.x;
    if (t == 0) s_len = 0;
    __syncthreads();
    if (t < W) {
        int tok = x[i * W + t];
        toks[t] = tok;
        if (tok > 0) atomicAdd(&s_len, 1);
    }
    __syncthreads();
    const int len = s_len;
    if (t < E) {
        float acc = 0.0f;
        for (int j = 0; j < len; ++j)
            acc += word_emb[toks[j] * E + t];   // coalesced across t
        float val = acc / (float)max(len, 1);
        sent[i * E + t] = val;
        atomicAdd(&doc_sum[t], val * (1.0f / (float)S));
    }
}

// K2: doc = tanh(doc_feat @ fc1_w.T + fc1_b); cvec = Wc + Ws @ doc
__global__ __launch_bounds__(128) void k_doc(const float* __restrict__ doc_sum,
                                             const float* __restrict__ fc1_w,
                                             const float* __restrict__ fc1_b,
                                             const float* __restrict__ Wc,
                                             const float* __restrict__ Ws,
                                             float* __restrict__ cvec) {
    __shared__ float s_df[E];
    __shared__ float s_doc[H];
    const int t = threadIdx.x;
    if (t < E) s_df[t] = doc_sum[t];
    __syncthreads();
    if (t < H) {
        float acc = fc1_b[t];
        for (int k = 0; k < E; ++k) acc += s_df[k] * fc1_w[t * E + k];
        s_doc[t] = tanhf(acc);
    }
    __syncthreads();
    if (t < H) {
        float c = Wc[t];
        for (int j = 0; j < H; ++j) c += Ws[t * H + j] * s_doc[j];
        cvec[t] = c;
    }
}

// K3: per-row padded layout for the scan.
// packed row i = 64 float4 slots; slot m = (hWr[2m], h[2m], hWr[2m+1], h[2m+1]),
// zeros for k>=100.  Slot 50 .x carries cq[i] = -log2e*(h.cvec + pos.Wp + b)
// (dead hWr position: its h is 0, so s stays 0, tanh(s)=0, contribution 0).
__global__ __launch_bounds__(128) void k_row(const float* __restrict__ sent,
                                             const float* __restrict__ fc2_w,
                                             const float* __restrict__ fc2_b,
                                             const float* __restrict__ Wr,
                                             const float* __restrict__ cvec,
                                             const float* __restrict__ pos_emb,
                                             const float* __restrict__ Wp,
                                             const float* __restrict__ bptr,
                                             float* __restrict__ packed) {
    __shared__ float s_sent[E];
    __shared__ float s_h[H];
    __shared__ float red[128];
    const int i = blockIdx.x, t = threadIdx.x;
    float* row = packed + (size_t)i * 256;
    if (t < E) s_sent[t] = sent[i * E + t];
    __syncthreads();
    float hv = 0.0f;
    if (t < H) {
        float acc = fc2_b[t];
        for (int k = 0; k < E; ++k) acc += s_sent[k] * fc2_w[t * E + k];
        hv = tanhf(acc);
        s_h[t] = hv;
    }
    __syncthreads();
    {
        const int m = t >> 1, o = (t & 1) * 2;
        if (t < H) {
            float acc = 0.0f;
            for (int k = 0; k < H; ++k) acc += s_h[k] * Wr[k * H + t];   // coalesced across t
            row[m * 4 + o]     = acc;  // hWr
            row[m * 4 + o + 1] = hv;   // h
        } else {
            if (t != 100) row[m * 4 + o] = 0.0f;   // element 200 reserved for cq
            row[m * 4 + o + 1] = 0.0f;
        }
    }
    float p = 0.0f;
    if (t < H) p = hv * cvec[t];
    if (t < PD) p += pos_emb[i * PD + t] * Wp[t];
    red[t] = p;
    __syncthreads();
    for (int m = 64; m > 0; m >>= 1) {
        if (t < m) red[t] += red[t + m];
        __syncthreads();
    }
    if (t == 0) row[200] = -1.44269504f * (red[0] + bptr[0]);  // slot 50 .x
}

// K4: the sequential scan. One wave; lane l owns k=2l (s0) and k=2l+1 (s1).
// ONE pure dwordx4 load per lane per step, consumed DEPTH steps later;
// cq recovered via readlane(ca.x, 50); output buffered per-lane, stored
// coalesced every 64 steps (no exec-mask dance on the critical path).
__global__ __launch_bounds__(64) void k_scan(const float4* __restrict__ packed,
                                             float* __restrict__ out) {
    const int l = threadIdx.x;

    float s0 = 0.0f, s1 = 0.0f, probbuf = 0.0f;

    float4 A[DEPTH];
    #pragma unroll
    for (int u = 0; u < DEPTH; ++u)
        A[u] = packed[(size_t)u * 64 + l];

    for (int base = 0; base < S; base += DEPTH) {
        #pragma unroll
        for (int u = 0; u < DEPTH; ++u) {
            const int i = base + u;
            const float4 ca = A[u];
            // branch-free clamped prefetch: pure load, nothing reads it for DEPTH steps
            const int j = (i + DEPTH < S) ? (i + DEPTH) : (S - 1);
            A[u] = packed[(size_t)j * 64 + l];

            const float q = __int_as_float(
                __builtin_amdgcn_readlane(__float_as_int(ca.x), 50));
            float t0 = fast_tanh(s0);
            float t1 = fast_tanh(s1);
            float part = fmaf(ca.x, t0, ca.z * t1);
            float total = wave_sum_bcast(part);
            // prob = sigmoid(pre - total) = 1/(1 + exp2(log2e*total + q))
            float e = exp2f(fmaf(1.44269504f, total, q));
            float prob = fast_rcp(1.0f + e);
            s0 = fmaf(ca.y, prob, s0);
            s1 = fmaf(ca.w, prob, s1);
            probbuf = (l == (i & 63)) ? prob : probbuf;   // off the s-chain
        }
        if ((base & 63) == 56)
            out[(base & ~63) + l] = probbuf;   // coalesced, once per 64 steps
    }
}

extern "C" void kernel_launch(void* const* d_in, const int* in_sizes, int n_in,
                              void* d_out, int out_size, void* d_ws, size_t ws_size,
                              hipStream_t stream) {
    const int*   x        = (const int*)  d_in[0];
    const float* word_emb = (const float*)d_in[1];
    const float* pos_emb  = (const float*)d_in[2];
    const float* fc1_w    = (const float*)d_in[3];
    const float* fc1_b    = (const float*)d_in[4];
    const float* fc2_w    = (const float*)d_in[5];
    const float* fc2_b    = (const float*)d_in[6];
    const float* Wc       = (const float*)d_in[7];
    const float* Ws       = (const float*)d_in[8];
    const float* Wr       = (const float*)d_in[9];
    const float* Wp       = (const float*)d_in[10];
    const float* bptr     = (const float*)d_in[11];
    float* out = (float*)d_out;

    float* wsf      = (float*)d_ws;
    float* doc_sum  = wsf;                 // 128 (zeroed each call)
    float* cvec     = wsf + 128;           // 128
    float* sent     = wsf + 256;           // S*E = 204800
    float* packed   = sent + S * E;        // S*256 = 524288 (16B-aligned offset)

    hipMemsetAsync(doc_sum, 0, E * sizeof(float), stream);
    k_sent<<<S, 128, 0, stream>>>(x, word_emb, sent, doc_sum);
    k_doc<<<1, 128, 0, stream>>>(doc_sum, fc1_w, fc1_b, Wc, Ws, cvec);
    k_row<<<S, 128, 0, stream>>>(sent, fc2_w, fc2_b, Wr, cvec, pos_emb, Wp, bptr, packed);
    k_scan<<<1, 64, 0, stream>>>((const float4*)packed, out);
}

// Round 6
// 419.828 us; speedup vs baseline: 2.0535x; 1.0129x over previous
//
#include <hip/hip_runtime.h>
#include <hip/hip_bf16.h>

// Problem constants (from reference)
#define S 2048
#define W 96
#define E 100
#define H 100
#define PD 50
#define DEPTH 8   // scan prefetch pipeline depth

__device__ __forceinline__ float fast_rcp(float x) { return __builtin_amdgcn_rcpf(x); }

// Overflow-safe fast tanh: e = exp(-2|x|) in (0,1], never overflows.
__device__ __forceinline__ float fast_tanh(float x) {
    float ax = fabsf(x);
    float e  = __expf(-2.0f * ax);
    float r  = (1.0f - e) * fast_rcp(1.0f + e);
    return copysignf(r, x);
}

// One DPP reduction stage: x += dpp_move(x). VALU latency, no LDS.
template<int CTRL, int RM, bool BND>
__device__ __forceinline__ float dpp_add(float x) {
    int t = __builtin_amdgcn_update_dpp(0, __float_as_int(x), CTRL, RM, 0xf, BND);
    return x + __int_as_float(t);
}

// Full-wave (64-lane) sum; returns total as a wave-uniform value.
__device__ __forceinline__ float wave_sum_bcast(float x) {
    x = dpp_add<0x111, 0xf, true >(x);  // row_shr:1
    x = dpp_add<0x112, 0xf, true >(x);  // row_shr:2
    x = dpp_add<0x114, 0xf, true >(x);  // row_shr:4
    x = dpp_add<0x118, 0xf, true >(x);  // row_shr:8
    x = dpp_add<0x142, 0xa, false>(x);  // row_bcast:15 -> rows 1,3
    x = dpp_add<0x143, 0xc, false>(x);  // row_bcast:31 -> rows 2,3
    return __int_as_float(__builtin_amdgcn_readlane(__float_as_int(x), 63));
}

// K1: ragged-prefix mean pool over word embeddings + doc_feat accumulation
__global__ __launch_bounds__(128) void k_sent(const int* __restrict__ x,
                                              const float* __restrict__ word_emb,
                                              float* __restrict__ sent,
                                              float* __restrict__ doc_sum) {
    __shared__ int toks[W];
    __shared__ int s_len;
    const int i = blockIdx.x, t = threadIdx.x;
    if (t == 0) s_len = 0;
    __syncthreads();
    if (t < W) {
        int tok = x[i * W + t];
        toks[t] = tok;
        if (tok > 0) atomicAdd(&s_len, 1);
    }
    __syncthreads();
    const int len = s_len;
    if (t < E) {
        float acc = 0.0f;
        for (int j = 0; j < len; ++j)
            acc += word_emb[toks[j] * E + t];   // coalesced across t
        float val = acc / (float)max(len, 1);
        sent[i * E + t] = val;
        atomicAdd(&doc_sum[t], val * (1.0f / (float)S));
    }
}

// K2: doc = tanh(doc_feat @ fc1_w.T + fc1_b); cvec = Wc + Ws @ doc
__global__ __launch_bounds__(128) void k_doc(const float* __restrict__ doc_sum,
                                             const float* __restrict__ fc1_w,
                                             const float* __restrict__ fc1_b,
                                             const float* __restrict__ Wc,
                                             const float* __restrict__ Ws,
                                             float* __restrict__ cvec) {
    __shared__ float s_df[E];
    __shared__ float s_doc[H];
    const int t = threadIdx.x;
    if (t < E) s_df[t] = doc_sum[t];
    __syncthreads();
    if (t < H) {
        float acc = fc1_b[t];
        for (int k = 0; k < E; ++k) acc += s_df[k] * fc1_w[t * E + k];
        s_doc[t] = tanhf(acc);
    }
    __syncthreads();
    if (t < H) {
        float c = Wc[t];
        for (int j = 0; j < H; ++j) c += Ws[t * H + j] * s_doc[j];
        cvec[t] = c;
    }
}

// K3: per-row padded layout for the scan.
// packed row i = 64 float4 slots; slot m = (hWr[2m], h[2m], hWr[2m+1], h[2m+1]),
// zeros for k>=100.  Slot 50 .x carries cq[i] = -log2e*(h.cvec + pos.Wp + b)
// (dead hWr position: its h is 0, so s stays 0, tanh(s)=0, contribution 0).
__global__ __launch_bounds__(128) void k_row(const float* __restrict__ sent,
                                             const float* __restrict__ fc2_w,
                                             const float* __restrict__ fc2_b,
                                             const float* __restrict__ Wr,
                                             const float* __restrict__ cvec,
                                             const float* __restrict__ pos_emb,
                                             const float* __restrict__ Wp,
                                             const float* __restrict__ bptr,
                                             float* __restrict__ packed) {
    __shared__ float s_sent[E];
    __shared__ float s_h[H];
    __shared__ float red[128];
    const int i = blockIdx.x, t = threadIdx.x;
    float* row = packed + (size_t)i * 256;
    if (t < E) s_sent[t] = sent[i * E + t];
    __syncthreads();
    float hv = 0.0f;
    if (t < H) {
        float acc = fc2_b[t];
        for (int k = 0; k < E; ++k) acc += s_sent[k] * fc2_w[t * E + k];
        hv = tanhf(acc);
        s_h[t] = hv;
    }
    __syncthreads();
    {
        const int m = t >> 1, o = (t & 1) * 2;
        if (t < H) {
            float acc = 0.0f;
            for (int k = 0; k < H; ++k) acc += s_h[k] * Wr[k * H + t];   // coalesced across t
            row[m * 4 + o]     = acc;  // hWr
            row[m * 4 + o + 1] = hv;   // h
        } else {
            if (t != 100) row[m * 4 + o] = 0.0f;   // element 200 reserved for cq
            row[m * 4 + o + 1] = 0.0f;
        }
    }
    float p = 0.0f;
    if (t < H) p = hv * cvec[t];
    if (t < PD) p += pos_emb[i * PD + t] * Wp[t];
    red[t] = p;
    __syncthreads();
    for (int m = 64; m > 0; m >>= 1) {
        if (t < m) red[t] += red[t + m];
        __syncthreads();
    }
    if (t == 0) row[200] = -1.44269504f * (red[0] + bptr[0]);  // slot 50 .x
}

// K4: the sequential scan. One wave; lane l owns k=2l (s0) and k=2l+1 (s1).
// 8 NAMED float4 registers hold the in-flight pipeline (no array indexing);
// __launch_bounds__(64,1) gives the allocator the full VGPR file so it has
// no occupancy incentive to sink the loads. Prefetch address is a pure
// pointer increment (packed is zero-padded by DEPTH rows, no clamp).
__global__ __launch_bounds__(64, 1) void k_scan(const float4* __restrict__ packed,
                                                float* __restrict__ out) {
    const int l = threadIdx.x;

    float s0 = 0.0f, s1 = 0.0f, probbuf = 0.0f;

    const float4* pf = packed + l;
    float4 a0 = pf[0 * 64], a1 = pf[1 * 64], a2 = pf[2 * 64], a3 = pf[3 * 64],
           a4 = pf[4 * 64], a5 = pf[5 * 64], a6 = pf[6 * 64], a7 = pf[7 * 64];
    pf += DEPTH * 64;

#define SCAN_STEP(AR, IDX)                                                    \
    {                                                                         \
        const float4 ca = AR;                                                 \
        AR = *pf;  pf += 64;   /* pure prefetch, consumed DEPTH steps later */\
        const float q = __int_as_float(                                       \
            __builtin_amdgcn_readlane(__float_as_int(ca.x), 50));             \
        float t0 = fast_tanh(s0);                                             \
        float t1 = fast_tanh(s1);                                             \
        float part = fmaf(ca.x, t0, ca.z * t1);                               \
        float total = wave_sum_bcast(part);                                   \
        float e = exp2f(fmaf(1.44269504f, total, q));                         \
        float prob = fast_rcp(1.0f + e);                                      \
        s0 = fmaf(ca.y, prob, s0);                                            \
        s1 = fmaf(ca.w, prob, s1);                                            \
        probbuf = (l == ((base + IDX) & 63)) ? prob : probbuf;                \
    }

    for (int base = 0; base < S; base += DEPTH) {
        SCAN_STEP(a0, 0) SCAN_STEP(a1, 1) SCAN_STEP(a2, 2) SCAN_STEP(a3, 3)
        SCAN_STEP(a4, 4) SCAN_STEP(a5, 5) SCAN_STEP(a6, 6) SCAN_STEP(a7, 7)
        if ((base & 63) == 56)
            out[(base & ~63) + l] = probbuf;   // coalesced, once per 64 steps
    }
#undef SCAN_STEP
}

extern "C" void kernel_launch(void* const* d_in, const int* in_sizes, int n_in,
                              void* d_out, int out_size, void* d_ws, size_t ws_size,
                              hipStream_t stream) {
    const int*   x        = (const int*)  d_in[0];
    const float* word_emb = (const float*)d_in[1];
    const float* pos_emb  = (const float*)d_in[2];
    const float* fc1_w    = (const float*)d_in[3];
    const float* fc1_b    = (const float*)d_in[4];
    const float* fc2_w    = (const float*)d_in[5];
    const float* fc2_b    = (const float*)d_in[6];
    const float* Wc       = (const float*)d_in[7];
    const float* Ws       = (const float*)d_in[8];
    const float* Wr       = (const float*)d_in[9];
    const float* Wp       = (const float*)d_in[10];
    const float* bptr     = (const float*)d_in[11];
    float* out = (float*)d_out;

    float* wsf      = (float*)d_ws;
    float* doc_sum  = wsf;                 // 128 (zeroed each call)
    float* cvec     = wsf + 128;           // 128
    float* sent     = wsf + 256;           // S*E = 204800
    float* packed   = sent + S * E;        // (S+DEPTH)*256 floats, 16B-aligned offset

    hipMemsetAsync(doc_sum, 0, E * sizeof(float), stream);
    hipMemsetAsync(packed + (size_t)S * 256, 0, DEPTH * 256 * sizeof(float), stream);
    k_sent<<<S, 128, 0, stream>>>(x, word_emb, sent, doc_sum);
    k_doc<<<1, 128, 0, stream>>>(doc_sum, fc1_w, fc1_b, Wc, Ws, cvec);
    k_row<<<S, 128, 0, stream>>>(sent, fc2_w, fc2_b, Wr, cvec, pos_emb, Wp, bptr, packed);
    k_scan<<<1, 64, 0, stream>>>((const float4*)packed, out);
}

// Round 8
// 381.391 us; speedup vs baseline: 2.2605x; 1.1008x over previous
//
#include <hip/hip_runtime.h>
#include <hip/hip_bf16.h>

// Problem constants (from reference)
#define S 2048
#define W 96
#define E 100
#define H 100
#define PD 50

typedef float f32x4 __attribute__((ext_vector_type(4)));

__device__ __forceinline__ float fast_rcp(float x) { return __builtin_amdgcn_rcpf(x); }

// Overflow-safe fast tanh: e = exp(-2|x|) in (0,1], never overflows.
__device__ __forceinline__ float fast_tanh(float x) {
    float ax = fabsf(x);
    float e  = __expf(-2.0f * ax);
    float r  = (1.0f - e) * fast_rcp(1.0f + e);
    return copysignf(r, x);
}

// One DPP reduction stage: x += dpp_move(x). VALU latency, no LDS.
template<int CTRL, int RM, bool BND>
__device__ __forceinline__ float dpp_add(float x) {
    int t = __builtin_amdgcn_update_dpp(0, __float_as_int(x), CTRL, RM, 0xf, BND);
    return x + __int_as_float(t);
}

// Full-wave (64-lane) sum; returns total as a wave-uniform value.
__device__ __forceinline__ float wave_sum_bcast(float x) {
    x = dpp_add<0x111, 0xf, true >(x);  // row_shr:1
    x = dpp_add<0x112, 0xf, true >(x);  // row_shr:2
    x = dpp_add<0x114, 0xf, true >(x);  // row_shr:4
    x = dpp_add<0x118, 0xf, true >(x);  // row_shr:8
    x = dpp_add<0x142, 0xa, false>(x);  // row_bcast:15 -> rows 1,3
    x = dpp_add<0x143, 0xc, false>(x);  // row_bcast:31 -> rows 2,3
    return __int_as_float(__builtin_amdgcn_readlane(__float_as_int(x), 63));
}

// K1: ragged-prefix mean pool over word embeddings + doc_feat accumulation
__global__ __launch_bounds__(128) void k_sent(const int* __restrict__ x,
                                              const float* __restrict__ word_emb,
                                              float* __restrict__ sent,
                                              float* __restrict__ doc_sum) {
    __shared__ int toks[W];
    __shared__ int s_len;
    const int i = blockIdx.x, t = threadIdx.x;
    if (t == 0) s_len = 0;
    __syncthreads();
    if (t < W) {
        int tok = x[i * W + t];
        toks[t] = tok;
        if (tok > 0) atomicAdd(&s_len, 1);
    }
    __syncthreads();
    const int len = s_len;
    if (t < E) {
        float acc = 0.0f;
        for (int j = 0; j < len; ++j)
            acc += word_emb[toks[j] * E + t];   // coalesced across t
        float val = acc / (float)max(len, 1);
        sent[i * E + t] = val;
        atomicAdd(&doc_sum[t], val * (1.0f / (float)S));
    }
}

// K2: doc = tanh(doc_feat @ fc1_w.T + fc1_b); cvec = Wc + Ws @ doc
__global__ __launch_bounds__(128) void k_doc(const float* __restrict__ doc_sum,
                                             const float* __restrict__ fc1_w,
                                             const float* __restrict__ fc1_b,
                                             const float* __restrict__ Wc,
                                             const float* __restrict__ Ws,
                                             float* __restrict__ cvec) {
    __shared__ float s_df[E];
    __shared__ float s_doc[H];
    const int t = threadIdx.x;
    if (t < E) s_df[t] = doc_sum[t];
    __syncthreads();
    if (t < H) {
        float acc = fc1_b[t];
        for (int k = 0; k < E; ++k) acc += s_df[k] * fc1_w[t * E + k];
        s_doc[t] = tanhf(acc);
    }
    __syncthreads();
    if (t < H) {
        float c = Wc[t];
        for (int j = 0; j < H; ++j) c += Ws[t * H + j] * s_doc[j];
        cvec[t] = c;
    }
}

// K3: per-row padded layout for the scan.
// packed row i = 64 float4 slots; slot m = (hWr[2m], h[2m], hWr[2m+1], h[2m+1]),
// zeros for k>=100.  Slot 50 .x carries cq[i] = -log2e*(h.cvec + pos.Wp + b)
// (dead hWr position: its h is 0, so s stays 0, tanh(s)=0, contribution 0).
__global__ __launch_bounds__(128) void k_row(const float* __restrict__ sent,
                                             const float* __restrict__ fc2_w,
                                             const float* __restrict__ fc2_b,
                                             const float* __restrict__ Wr,
                                             const float* __restrict__ cvec,
                                             const float* __restrict__ pos_emb,
                                             const float* __restrict__ Wp,
                                             const float* __restrict__ bptr,
                                             float* __restrict__ packed) {
    __shared__ float s_sent[E];
    __shared__ float s_h[H];
    __shared__ float red[128];
    const int i = blockIdx.x, t = threadIdx.x;
    float* row = packed + (size_t)i * 256;
    if (t < E) s_sent[t] = sent[i * E + t];
    __syncthreads();
    float hv = 0.0f;
    if (t < H) {
        float acc = fc2_b[t];
        for (int k = 0; k < E; ++k) acc += s_sent[k] * fc2_w[t * E + k];
        hv = tanhf(acc);
        s_h[t] = hv;
    }
    __syncthreads();
    {
        const int m = t >> 1, o = (t & 1) * 2;
        if (t < H) {
            float acc = 0.0f;
            for (int k = 0; k < H; ++k) acc += s_h[k] * Wr[k * H + t];   // coalesced across t
            row[m * 4 + o]     = acc;  // hWr
            row[m * 4 + o + 1] = hv;   // h
        } else {
            if (t != 100) row[m * 4 + o] = 0.0f;   // element 200 reserved for cq
            row[m * 4 + o + 1] = 0.0f;
        }
    }
    float p = 0.0f;
    if (t < H) p = hv * cvec[t];
    if (t < PD) p += pos_emb[i * PD + t] * Wp[t];
    red[t] = p;
    __syncthreads();
    for (int m = 64; m > 0; m >>= 1) {
        if (t < m) red[t] += red[t + m];
        __syncthreads();
    }
    if (t == 0) row[200] = -1.44269504f * (red[0] + bptr[0]);  // slot 50 .x
}

// K4: the sequential scan, BATCH double-buffered manual pipeline.
// Two named register sets X (x0..x7) and Y (y0..y7). Iteration:
//   ISSUE8(Y, next 8 rows)  -> volatile asm, cannot be sunk
//   COMPUTE8(X)             -> X is fully landed (waited last iteration)
//   s_waitcnt vmcnt(0) + sched_barrier(0)  -> Y lands; issued ~1400cy earlier
// then roles swap (compile-time). No asm-loaded register is ever live across
// a loop back-edge while in flight => RA phi-copies always read landed data
// (this was R7's corruption mechanism).
__global__ __launch_bounds__(64, 1) void k_scan(const f32x4* __restrict__ packed,
                                                float* __restrict__ out) {
    const int l = threadIdx.x;
    const f32x4* pf = packed + l;

    float s0 = 0.0f, s1 = 0.0f, probbuf = 0.0f;

    f32x4 x0, x1, x2, x3, x4, x5, x6, x7;
    f32x4 y0, y1, y2, y3, y4, y5, y6, y7;

#define ISSUE(AR, PTR) \
    asm volatile("global_load_dwordx4 %0, %1, off" : "=v"(AR) : "v"(PTR))
#define ISSUE8(P0, P1, P2, P3, P4, P5, P6, P7)                                \
    ISSUE(P0, pf + 0 * 64); ISSUE(P1, pf + 1 * 64);                           \
    ISSUE(P2, pf + 2 * 64); ISSUE(P3, pf + 3 * 64);                           \
    ISSUE(P4, pf + 4 * 64); ISSUE(P5, pf + 5 * 64);                           \
    ISSUE(P6, pf + 6 * 64); ISSUE(P7, pf + 7 * 64);                           \
    pf += 8 * 64;
#define WAIT_ALL()                                                            \
    asm volatile("s_waitcnt vmcnt(0)" ::: "memory");                          \
    __builtin_amdgcn_sched_barrier(0);

#define STEP(CA_, IDX, G)                                                     \
    {                                                                         \
        const f32x4 ca = CA_;                                                 \
        const float q = __int_as_float(                                       \
            __builtin_amdgcn_readlane(__float_as_int(ca.x), 50));             \
        float t0 = fast_tanh(s0);                                             \
        float t1 = fast_tanh(s1);                                             \
        float part = fmaf(ca.x, t0, ca.z * t1);                               \
        float total = wave_sum_bcast(part);                                   \
        float e = exp2f(fmaf(1.44269504f, total, q));                         \
        float prob = fast_rcp(1.0f + e);                                      \
        s0 = fmaf(ca.y, prob, s0);                                            \
        s1 = fmaf(ca.w, prob, s1);                                            \
        probbuf = (l == ((G + IDX) & 63)) ? prob : probbuf;                   \
    }
#define COMPUTE8(P0, P1, P2, P3, P4, P5, P6, P7, G)                           \
    STEP(P0, 0, G) STEP(P1, 1, G) STEP(P2, 2, G) STEP(P3, 3, G)               \
    STEP(P4, 4, G) STEP(P5, 5, G) STEP(P6, 6, G) STEP(P7, 7, G)               \
    if (((G) & 63) == 56) out[((G) & ~63) + l] = probbuf;

    // Preload batch 0 into X and land it.
    ISSUE8(x0, x1, x2, x3, x4, x5, x6, x7)
    WAIT_ALL()

    for (int base = 0; base < S; base += 16) {
        ISSUE8(y0, y1, y2, y3, y4, y5, y6, y7)            // rows base+8..base+15
        COMPUTE8(x0, x1, x2, x3, x4, x5, x6, x7, base)    // rows base..base+7
        WAIT_ALL()                                        // Y landed
        ISSUE8(x0, x1, x2, x3, x4, x5, x6, x7)            // rows base+16..base+23
        COMPUTE8(y0, y1, y2, y3, y4, y5, y6, y7, base + 8)
        WAIT_ALL()                                        // X landed
    }
#undef COMPUTE8
#undef STEP
#undef WAIT_ALL
#undef ISSUE8
#undef ISSUE
}

extern "C" void kernel_launch(void* const* d_in, const int* in_sizes, int n_in,
                              void* d_out, int out_size, void* d_ws, size_t ws_size,
                              hipStream_t stream) {
    const int*   x        = (const int*)  d_in[0];
    const float* word_emb = (const float*)d_in[1];
    const float* pos_emb  = (const float*)d_in[2];
    const float* fc1_w    = (const float*)d_in[3];
    const float* fc1_b    = (const float*)d_in[4];
    const float* fc2_w    = (const float*)d_in[5];
    const float* fc2_b    = (const float*)d_in[6];
    const float* Wc       = (const float*)d_in[7];
    const float* Ws       = (const float*)d_in[8];
    const float* Wr       = (const float*)d_in[9];
    const float* Wp       = (const float*)d_in[10];
    const float* bptr     = (const float*)d_in[11];
    float* out = (float*)d_out;

    float* wsf      = (float*)d_ws;
    float* doc_sum  = wsf;                 // 128 (zeroed each call)
    float* cvec     = wsf + 128;           // 128
    float* sent     = wsf + 256;           // S*E = 204800
    float* packed   = sent + S * E;        // (S+16)*256 floats, 16B-aligned offset

    hipMemsetAsync(doc_sum, 0, E * sizeof(float), stream);
    hipMemsetAsync(packed + (size_t)S * 256, 0, 16 * 256 * sizeof(float), stream);
    k_sent<<<S, 128, 0, stream>>>(x, word_emb, sent, doc_sum);
    k_doc<<<1, 128, 0, stream>>>(doc_sum, fc1_w, fc1_b, Wc, Ws, cvec);
    k_row<<<S, 128, 0, stream>>>(sent, fc2_w, fc2_b, Wr, cvec, pos_emb, Wp, bptr, packed);
    k_scan<<<1, 64, 0, stream>>>((const f32x4*)packed, out);
}

// Round 9
// 350.449 us; speedup vs baseline: 2.4601x; 1.0883x over previous
//
#include <hip/hip_runtime.h>
#include <hip/hip_bf16.h>

// Problem constants (from reference)
#define S 2048
#define W 96
#define E 100
#define H 100
#define PD 50

typedef float f32x4 __attribute__((ext_vector_type(4)));

__device__ __forceinline__ float fast_rcp(float x) { return __builtin_amdgcn_rcpf(x); }

// Overflow-safe fast tanh: e = exp(-2|x|) in (0,1], never overflows.
__device__ __forceinline__ float fast_tanh(float x) {
    float ax = fabsf(x);
    float e  = __expf(-2.0f * ax);
    float r  = (1.0f - e) * fast_rcp(1.0f + e);
    return copysignf(r, x);
}

// One DPP reduction stage: x += dpp_move(x). VALU latency, no LDS.
template<int CTRL, int RM, bool BND>
__device__ __forceinline__ float dpp_add(float x) {
    int t = __builtin_amdgcn_update_dpp(0, __float_as_int(x), CTRL, RM, 0xf, BND);
    return x + __int_as_float(t);
}

// Full-wave (64-lane) sum; returns total as a wave-uniform value.
__device__ __forceinline__ float wave_sum_bcast(float x) {
    x = dpp_add<0x111, 0xf, true >(x);  // row_shr:1
    x = dpp_add<0x112, 0xf, true >(x);  // row_shr:2
    x = dpp_add<0x114, 0xf, true >(x);  // row_shr:4
    x = dpp_add<0x118, 0xf, true >(x);  // row_shr:8
    x = dpp_add<0x142, 0xa, false>(x);  // row_bcast:15 -> rows 1,3
    x = dpp_add<0x143, 0xc, false>(x);  // row_bcast:31 -> rows 2,3
    return __int_as_float(__builtin_amdgcn_readlane(__float_as_int(x), 63));
}

// K1: ragged-prefix mean pool over word embeddings + doc_feat accumulation
__global__ __launch_bounds__(128) void k_sent(const int* __restrict__ x,
                                              const float* __restrict__ word_emb,
                                              float* __restrict__ sent,
                                              float* __restrict__ doc_sum) {
    __shared__ int toks[W];
    __shared__ int s_len;
    const int i = blockIdx.x, t = threadIdx.x;
    if (t == 0) s_len = 0;
    __syncthreads();
    if (t < W) {
        int tok = x[i * W + t];
        toks[t] = tok;
        if (tok > 0) atomicAdd(&s_len, 1);
    }
    __syncthreads();
    const int len = s_len;
    if (t < E) {
        float acc = 0.0f;
        for (int j = 0; j < len; ++j)
            acc += word_emb[toks[j] * E + t];   // coalesced across t
        float val = acc / (float)max(len, 1);
        sent[i * E + t] = val;
        atomicAdd(&doc_sum[t], val * (1.0f / (float)S));
    }
}

// K2: doc = tanh(doc_feat @ fc1_w.T + fc1_b); cvec = Wc + Ws @ doc
__global__ __launch_bounds__(128) void k_doc(const float* __restrict__ doc_sum,
                                             const float* __restrict__ fc1_w,
                                             const float* __restrict__ fc1_b,
                                             const float* __restrict__ Wc,
                                             const float* __restrict__ Ws,
                                             float* __restrict__ cvec) {
    __shared__ float s_df[E];
    __shared__ float s_doc[H];
    const int t = threadIdx.x;
    if (t < E) s_df[t] = doc_sum[t];
    __syncthreads();
    if (t < H) {
        float acc = fc1_b[t];
        for (int k = 0; k < E; ++k) acc += s_df[k] * fc1_w[t * E + k];
        s_doc[t] = tanhf(acc);
    }
    __syncthreads();
    if (t < H) {
        float c = Wc[t];
        for (int j = 0; j < H; ++j) c += Ws[t * H + j] * s_doc[j];
        cvec[t] = c;
    }
}

// K3: per-row padded layout for the scan.
// packed row i = 64 float4 slots; slot m = (hWr[2m], h[2m], hWr[2m+1], h[2m+1]),
// zeros for k>=100.  Slot 50 .x carries cq[i] = -log2e*(h.cvec + pos.Wp + b)
// (dead hWr position: its h is 0, so s stays 0, tanh(s)=0, contribution 0).
__global__ __launch_bounds__(128) void k_row(const float* __restrict__ sent,
                                             const float* __restrict__ fc2_w,
                                             const float* __restrict__ fc2_b,
                                             const float* __restrict__ Wr,
                                             const float* __restrict__ cvec,
                                             const float* __restrict__ pos_emb,
                                             const float* __restrict__ Wp,
                                             const float* __restrict__ bptr,
                                             float* __restrict__ packed) {
    __shared__ float s_sent[E];
    __shared__ float s_h[H];
    __shared__ float red[128];
    const int i = blockIdx.x, t = threadIdx.x;
    float* row = packed + (size_t)i * 256;
    if (t < E) s_sent[t] = sent[i * E + t];
    __syncthreads();
    float hv = 0.0f;
    if (t < H) {
        float acc = fc2_b[t];
        for (int k = 0; k < E; ++k) acc += s_sent[k] * fc2_w[t * E + k];
        hv = tanhf(acc);
        s_h[t] = hv;
    }
    __syncthreads();
    {
        const int m = t >> 1, o = (t & 1) * 2;
        if (t < H) {
            float acc = 0.0f;
            for (int k = 0; k < H; ++k) acc += s_h[k] * Wr[k * H + t];   // coalesced across t
            row[m * 4 + o]     = acc;  // hWr
            row[m * 4 + o + 1] = hv;   // h
        } else {
            if (t != 100) row[m * 4 + o] = 0.0f;   // element 200 reserved for cq
            row[m * 4 + o + 1] = 0.0f;
        }
    }
    float p = 0.0f;
    if (t < H) p = hv * cvec[t];
    if (t < PD) p += pos_emb[i * PD + t] * Wp[t];
    red[t] = p;
    __syncthreads();
    for (int m = 64; m > 0; m >>= 1) {
        if (t < m) red[t] += red[t + m];
        __syncthreads();
    }
    if (t == 0) row[200] = -1.44269504f * (red[0] + bptr[0]);  // slot 50 .x
}

// K4: the sequential scan, BATCH double-buffered manual pipeline with a
// PINNED schedule. sched_barrier(0) on both sides of each ISSUE8 and before
// each WAIT prevents the pre-RA scheduler from hoisting compute above the
// issues (R8: it did exactly that, collapsing the overlap to VGPR=36).
// Regions: [WAIT|SB][SB ISSUE8 SB][COMPUTE8][SB WAIT] -> X and Y both live,
// loads fly under ~1500cy of compute, wait is free.
__global__ __launch_bounds__(64, 1) void k_scan(const f32x4* __restrict__ packed,
                                                float* __restrict__ out) {
    const int l = threadIdx.x;
    const f32x4* pf = packed + l;

    float s0 = 0.0f, s1 = 0.0f, probbuf = 0.0f;

    f32x4 x0, x1, x2, x3, x4, x5, x6, x7;
    f32x4 y0, y1, y2, y3, y4, y5, y6, y7;

#define SB() __builtin_amdgcn_sched_barrier(0)
#define ISSUE(AR, PTR) \
    asm volatile("global_load_dwordx4 %0, %1, off" : "=v"(AR) : "v"(PTR))
#define ISSUE8(P0, P1, P2, P3, P4, P5, P6, P7)                                \
    SB();                                                                     \
    ISSUE(P0, pf + 0 * 64); ISSUE(P1, pf + 1 * 64);                           \
    ISSUE(P2, pf + 2 * 64); ISSUE(P3, pf + 3 * 64);                           \
    ISSUE(P4, pf + 4 * 64); ISSUE(P5, pf + 5 * 64);                           \
    ISSUE(P6, pf + 6 * 64); ISSUE(P7, pf + 7 * 64);                           \
    pf += 8 * 64;                                                             \
    SB();
#define WAIT_ALL()                                                            \
    SB();                                                                     \
    asm volatile("s_waitcnt vmcnt(0)" ::: "memory");                          \
    SB();

#define STEP(CA_, IDX, G)                                                     \
    {                                                                         \
        const f32x4 ca = CA_;                                                 \
        const float q = __int_as_float(                                       \
            __builtin_amdgcn_readlane(__float_as_int(ca.x), 50));             \
        float t0 = fast_tanh(s0);                                             \
        float t1 = fast_tanh(s1);                                             \
        float part = fmaf(ca.x, t0, ca.z * t1);                               \
        float total = wave_sum_bcast(part);                                   \
        float e = exp2f(fmaf(1.44269504f, total, q));                         \
        float prob = fast_rcp(1.0f + e);                                      \
        s0 = fmaf(ca.y, prob, s0);                                            \
        s1 = fmaf(ca.w, prob, s1);                                            \
        probbuf = (l == ((G + IDX) & 63)) ? prob : probbuf;                   \
    }
#define COMPUTE8(P0, P1, P2, P3, P4, P5, P6, P7, G)                           \
    STEP(P0, 0, G) STEP(P1, 1, G) STEP(P2, 2, G) STEP(P3, 3, G)               \
    STEP(P4, 4, G) STEP(P5, 5, G) STEP(P6, 6, G) STEP(P7, 7, G)               \
    if (((G) & 63) == 56) out[((G) & ~63) + l] = probbuf;

    // Preload batch 0 into X and land it.
    ISSUE8(x0, x1, x2, x3, x4, x5, x6, x7)
    WAIT_ALL()

    for (int base = 0; base < S; base += 16) {
        ISSUE8(y0, y1, y2, y3, y4, y5, y6, y7)            // rows base+8..base+15
        COMPUTE8(x0, x1, x2, x3, x4, x5, x6, x7, base)    // rows base..base+7
        WAIT_ALL()                                        // Y landed (issued ~1500cy ago)
        ISSUE8(x0, x1, x2, x3, x4, x5, x6, x7)            // rows base+16..base+23
        COMPUTE8(y0, y1, y2, y3, y4, y5, y6, y7, base + 8)
        WAIT_ALL()                                        // X landed
    }
#undef COMPUTE8
#undef STEP
#undef WAIT_ALL
#undef ISSUE8
#undef ISSUE
#undef SB
}

extern "C" void kernel_launch(void* const* d_in, const int* in_sizes, int n_in,
                              void* d_out, int out_size, void* d_ws, size_t ws_size,
                              hipStream_t stream) {
    const int*   x        = (const int*)  d_in[0];
    const float* word_emb = (const float*)d_in[1];
    const float* pos_emb  = (const float*)d_in[2];
    const float* fc1_w    = (const float*)d_in[3];
    const float* fc1_b    = (const float*)d_in[4];
    const float* fc2_w    = (const float*)d_in[5];
    const float* fc2_b    = (const float*)d_in[6];
    const float* Wc       = (const float*)d_in[7];
    const float* Ws       = (const float*)d_in[8];
    const float* Wr       = (const float*)d_in[9];
    const float* Wp       = (const float*)d_in[10];
    const float* bptr     = (const float*)d_in[11];
    float* out = (float*)d_out;

    float* wsf      = (float*)d_ws;
    float* doc_sum  = wsf;                 // 128 (zeroed each call)
    float* cvec     = wsf + 128;           // 128
    float* sent     = wsf + 256;           // S*E = 204800
    float* packed   = sent + S * E;        // (S+16)*256 floats, 16B-aligned offset

    hipMemsetAsync(doc_sum, 0, E * sizeof(float), stream);
    hipMemsetAsync(packed + (size_t)S * 256, 0, 16 * 256 * sizeof(float), stream);
    k_sent<<<S, 128, 0, stream>>>(x, word_emb, sent, doc_sum);
    k_doc<<<1, 128, 0, stream>>>(doc_sum, fc1_w, fc1_b, Wc, Ws, cvec);
    k_row<<<S, 128, 0, stream>>>(sent, fc2_w, fc2_b, Wr, cvec, pos_emb, Wp, bptr, packed);
    k_scan<<<1, 64, 0, stream>>>((const f32x4*)packed, out);
}